// Round 1
// baseline (493.845 us; speedup 1.0000x reference)
//
#include <hip/hip_runtime.h>
#include <math.h>

#define N_G 512
#define IMG_H 324
#define IMG_W 332
#define N_C 120
#define HW (IMG_H*IMG_W)

// ws layout:
//   params : [512][8] floats {sx, sy, c00, c11, op_eff, depth, rx, ry}   (16 KB)
//   order  : [512] int                                                    (2 KB)
//   spec_s : [512][120] floats (depth-sorted spectral features)           (240 KB)

__global__ __launch_bounds__(512) void k_prep(
    const float* __restrict__ pos, const float* __restrict__ scales,
    const float* __restrict__ opac, const float* __restrict__ K,
    const float* __restrict__ E, float* __restrict__ params,
    int* __restrict__ order)
{
  __shared__ float sp[N_G][8];
  __shared__ float key[N_G];
  __shared__ int val[N_G];
  const int i = threadIdx.x;

  float p0 = pos[i*3+0], p1 = pos[i*3+1], p2 = pos[i*3+2];
  // cam = [p,1] @ E^T  (rows of E)
  float cam0 = E[0]*p0 + E[1]*p1 + E[2]*p2  + E[3];
  float cam1 = E[4]*p0 + E[5]*p1 + E[6]*p2  + E[7];
  float cam2 = E[8]*p0 + E[9]*p1 + E[10]*p2 + E[11];
  // proj = cam3 @ K^T
  float pr0 = K[0]*cam0 + K[1]*cam1 + K[2]*cam2;
  float pr1 = K[3]*cam0 + K[4]*cam1 + K[5]*cam2;
  float pr2 = K[6]*cam0 + K[7]*cam1 + K[8]*cam2;
  float inv = 1.0f/(pr2 + 1e-6f);
  float sx = pr0*inv, sy = pr1*inv;
  float depth = cam2;

  bool valid = (depth > 0.01f) && (depth < 100.0f)
            && (sx > -100.0f) && (sx < (float)IMG_W + 100.0f)
            && (sy > -100.0f) && (sy < (float)IMG_H + 100.0f);
  bool off = (sx < -(float)IMG_W) || (sx > 2.0f*(float)IMG_W)
          || (sy < -(float)IMG_H) || (sy > 2.0f*(float)IMG_H);
  bool skip = off || (!valid);

  float s0 = scales[i*3+0], s1 = scales[i*3+1];
  float v0 = s0*s0 + 1e-4f, v1 = s1*s1 + 1e-4f;
  float c00 = 1.0f/v0, c11 = 1.0f/v1;
  float op = skip ? 0.0f : opac[i];
  // cull radius: mahal cutoff 36 (alpha_raw < 1.6e-8) -> r = 6*sigma
  float rx = skip ? -1e9f : 6.0f*sqrtf(v0);
  float ry = skip ? -1e9f : 6.0f*sqrtf(v1);

  sp[i][0]=sx; sp[i][1]=sy; sp[i][2]=c00; sp[i][3]=c11;
  sp[i][4]=op; sp[i][5]=depth; sp[i][6]=rx; sp[i][7]=ry;
  key[i] = depth; val[i] = i;
  __syncthreads();

  // bitonic sort ascending by depth (512 elements, 512 threads)
  for (int k = 2; k <= N_G; k <<= 1) {
    for (int j = k >> 1; j > 0; j >>= 1) {
      int ixj = i ^ j;
      if (ixj > i) {
        bool up = ((i & k) == 0);
        float ki = key[i], kj = key[ixj];
        if ((ki > kj) == up) {
          key[i] = kj; key[ixj] = ki;
          int t = val[i]; val[i] = val[ixj]; val[ixj] = t;
        }
      }
      __syncthreads();
    }
  }

  int src = val[i];
  order[i] = src;
  #pragma unroll
  for (int kk = 0; kk < 8; ++kk) params[i*8 + kk] = sp[src][kk];
}

__global__ __launch_bounds__(128) void k_gather(
    const float* __restrict__ spec, const int* __restrict__ order,
    float* __restrict__ spec_s)
{
  int n = blockIdx.x;
  int c = threadIdx.x;
  if (c < N_C) spec_s[n*N_C + c] = spec[order[n]*N_C + c];
}

__global__ __launch_bounds__(256, 2) void k_render(
    const float* __restrict__ params, const float* __restrict__ spec_s,
    const float* __restrict__ tm, float* __restrict__ out)
{
  __shared__ float lp[N_G*8];
  for (int i = threadIdx.x; i < N_G*8; i += 256) lp[i] = params[i];
  __syncthreads();

  const int tx = threadIdx.x & 31;
  const int ty = threadIdx.x >> 5;
  const int x = blockIdx.x*32 + tx;
  const int y = blockIdx.y*8 + ty;
  const bool inb = (x < IMG_W) && (y < IMG_H);
  const float px = (float)min(x, IMG_W-1);
  const float py = (float)min(y, IMG_H-1);

  // wave covers a 32x2 pixel strip -> wave-uniform cull bbox
  const int wid = threadIdx.x >> 6;
  const float wxmin = (float)(blockIdx.x*32);
  const float wxmax = wxmin + 31.0f;
  const float wymin = (float)(blockIdx.y*8 + wid*2);
  const float wymax = wymin + 1.0f;

  float acc[N_C];
  #pragma unroll
  for (int c = 0; c < N_C; ++c) acc[c] = 0.0f;
  float T = 1.0f;        // transmittance = 1 - A
  float dacc = 0.0f;

  for (int g = 0; g < N_G; ++g) {
    float4 pA = *(const float4*)&lp[g*8];       // sx, sy, c00, c11
    float4 pB = *(const float4*)&lp[g*8 + 4];   // op, depth, rx, ry
    float sx = pA.x, sy = pA.y;
    bool hit = (sx + pB.z >= wxmin) && (sx - pB.z <= wxmax)
            && (sy + pB.w >= wymin) && (sy - pB.w <= wymax);
    if (!hit) continue;

    float dx = px - sx, dy = py - sy;
    float m = pA.z*dx*dx + pA.w*dy*dy;
    float araw = pB.x * __expf(-0.5f*m);
    float alpha = araw * T;
    T -= alpha;
    dacc += pB.y * alpha;

    const float* row = spec_s + g*N_C;   // g wave-uniform -> scalar-load friendly
    #pragma unroll
    for (int c = 0; c < N_C; c += 4) {
      float4 s4 = *(const float4*)(row + c);
      acc[c+0] += alpha*s4.x;
      acc[c+1] += alpha*s4.y;
      acc[c+2] += alpha*s4.z;
      acc[c+3] += alpha*s4.w;
    }
  }

  if (inb) {
    int pixi = y*IMG_W + x;
    float bgT = 1.0f * T;   // BG * (1 - A_final), BG = 1.0
    #pragma unroll 4
    for (int c = 0; c < N_C; ++c) {
      out[c*HW + pixi] = (acc[c] + bgT) * tm[c];
    }
    out[N_C*HW + pixi] = dacc;            // depth image
    out[N_C*HW + HW + pixi] = 1.0f - T;   // A_final
  }
}

extern "C" void kernel_launch(void* const* d_in, const int* in_sizes, int n_in,
                              void* d_out, int out_size, void* d_ws, size_t ws_size,
                              hipStream_t stream) {
  const float* pos    = (const float*)d_in[0];
  // d_in[1] rotations: unused by the reference
  const float* scales = (const float*)d_in[2];
  const float* opac   = (const float*)d_in[3];
  const float* spec   = (const float*)d_in[4];
  const float* tm     = (const float*)d_in[5];
  const float* K      = (const float*)d_in[6];
  const float* E      = (const float*)d_in[7];
  float* out = (float*)d_out;

  float* params = (float*)d_ws;
  int*   order  = (int*)((char*)d_ws + (size_t)N_G*8*4);
  float* spec_s = (float*)((char*)d_ws + (size_t)N_G*8*4 + (size_t)N_G*4);

  k_prep<<<1, 512, 0, stream>>>(pos, scales, opac, K, E, params, order);
  k_gather<<<N_G, 128, 0, stream>>>(spec, order, spec_s);
  dim3 grid((IMG_W + 31)/32, (IMG_H + 7)/8);
  k_render<<<grid, 256, 0, stream>>>(params, spec_s, tm, out);
}

// Round 2
// 261.493 us; speedup vs baseline: 1.8886x; 1.8886x over previous
//
#include <hip/hip_runtime.h>
#include <math.h>

#define N_G 512
#define IMG_H 324
#define IMG_W 332
#define N_C 120
#define HW (IMG_H*IMG_W)

// ws layout (all depth-sorted by k_prep):
//   bb : [512] float4 {xmin, xmax, ymin, ymax}   (8 KB)  cull bbox (6-sigma)
//   pc : [512] float4 {sx, sy, c00, c11}         (8 KB)
//   od : [512] float4 {op, depth, src_idx_bits}  (8 KB)

__global__ __launch_bounds__(512) void k_prep(
    const float* __restrict__ pos, const float* __restrict__ scales,
    const float* __restrict__ opac, const float* __restrict__ K,
    const float* __restrict__ E,
    float4* __restrict__ bb, float4* __restrict__ pc, float4* __restrict__ od)
{
  __shared__ float sp[N_G][8];
  __shared__ float key[N_G];
  __shared__ int val[N_G];
  const int i = threadIdx.x;

  float p0 = pos[i*3+0], p1 = pos[i*3+1], p2 = pos[i*3+2];
  // cam = [p,1] @ E^T  (rows of E)
  float cam0 = E[0]*p0 + E[1]*p1 + E[2]*p2  + E[3];
  float cam1 = E[4]*p0 + E[5]*p1 + E[6]*p2  + E[7];
  float cam2 = E[8]*p0 + E[9]*p1 + E[10]*p2 + E[11];
  // proj = cam3 @ K^T
  float pr0 = K[0]*cam0 + K[1]*cam1 + K[2]*cam2;
  float pr1 = K[3]*cam0 + K[4]*cam1 + K[5]*cam2;
  float pr2 = K[6]*cam0 + K[7]*cam1 + K[8]*cam2;
  float inv = 1.0f/(pr2 + 1e-6f);
  float sx = pr0*inv, sy = pr1*inv;
  float depth = cam2;

  bool valid = (depth > 0.01f) && (depth < 100.0f)
            && (sx > -100.0f) && (sx < (float)IMG_W + 100.0f)
            && (sy > -100.0f) && (sy < (float)IMG_H + 100.0f);
  bool off = (sx < -(float)IMG_W) || (sx > 2.0f*(float)IMG_W)
          || (sy < -(float)IMG_H) || (sy > 2.0f*(float)IMG_H);
  bool skip = off || (!valid);

  float s0 = scales[i*3+0], s1 = scales[i*3+1];
  float v0 = s0*s0 + 1e-4f, v1 = s1*s1 + 1e-4f;
  float c00 = 1.0f/v0, c11 = 1.0f/v1;
  float op = skip ? 0.0f : opac[i];
  // cull radius: mahal cutoff 36 (alpha_raw < 1.6e-8) -> r = 6*sigma
  float rx = 6.0f*sqrtf(v0);
  float ry = 6.0f*sqrtf(v1);
  // skip -> empty bbox (never intersects any wave strip)
  float xmin = skip ?  1e9f : sx - rx;
  float xmax = skip ? -1e9f : sx + rx;
  float ymin = skip ?  1e9f : sy - ry;
  float ymax = skip ? -1e9f : sy + ry;

  sp[i][0]=sx;   sp[i][1]=sy;   sp[i][2]=c00;  sp[i][3]=c11;
  sp[i][4]=op;   sp[i][5]=depth; sp[i][6]=xmin; sp[i][7]=xmax;
  // ymin/ymax recomputed from what we store? keep extra in two more slots:
  key[i] = depth; val[i] = i;
  __shared__ float ymn[N_G], ymx[N_G];
  ymn[i] = ymin; ymx[i] = ymax;
  __syncthreads();

  // bitonic sort ascending by depth (512 elements, 512 threads)
  for (int k = 2; k <= N_G; k <<= 1) {
    for (int j = k >> 1; j > 0; j >>= 1) {
      int ixj = i ^ j;
      if (ixj > i) {
        bool up = ((i & k) == 0);
        float ki = key[i], kj = key[ixj];
        if ((ki > kj) == up) {
          key[i] = kj; key[ixj] = ki;
          int t = val[i]; val[i] = val[ixj]; val[ixj] = t;
        }
      }
      __syncthreads();
    }
  }

  int src = val[i];
  bb[i] = make_float4(sp[src][6], sp[src][7], ymn[src], ymx[src]);
  pc[i] = make_float4(sp[src][0], sp[src][1], sp[src][2], sp[src][3]);
  od[i] = make_float4(sp[src][4], sp[src][5], __int_as_float(src), 0.0f);
}

// 256 threads: tid = [h:1][ty:3][tx:4], pixel tile 16x8, channel half h (60 ch).
// Wave w = tid>>6 covers a 16x4 pixel strip (h = w>>1, rows (w&1)*4..+3):
// the bbox test result is wave-uniform -> clean execz skip of the hit body.
#define ACC4(i) \
  { float4 s4 = *(const float4*)(row + 4*(i)); \
    a##i.x = fmaf(alpha, s4.x, a##i.x); \
    a##i.y = fmaf(alpha, s4.y, a##i.y); \
    a##i.z = fmaf(alpha, s4.z, a##i.z); \
    a##i.w = fmaf(alpha, s4.w, a##i.w); }

#define ST4(i) \
  { float4 t4 = *(const float4*)(tmh + 4*(i)); \
    out[(cbase + 4*(i) + 0)*HW + pixi] = (a##i.x + bgT)*t4.x; \
    out[(cbase + 4*(i) + 1)*HW + pixi] = (a##i.y + bgT)*t4.y; \
    out[(cbase + 4*(i) + 2)*HW + pixi] = (a##i.z + bgT)*t4.z; \
    out[(cbase + 4*(i) + 3)*HW + pixi] = (a##i.w + bgT)*t4.w; }

__global__ __launch_bounds__(256, 2) void k_render(
    const float4* __restrict__ bb, const float4* __restrict__ pc,
    const float4* __restrict__ od, const float* __restrict__ spec,
    const float* __restrict__ tm, float* __restrict__ out)
{
  const int tid = threadIdx.x;
  const int h  = tid >> 7;          // channel half: 0 -> ch 0..59, 1 -> 60..119
  const int tx = tid & 15;
  const int ty = (tid >> 4) & 7;
  const int x = blockIdx.x*16 + tx;
  const int y = blockIdx.y*8 + ty;
  const bool inb = (x < IMG_W) && (y < IMG_H);
  const float px = (float)min(x, IMG_W-1);
  const float py = (float)min(y, IMG_H-1);

  // wave-uniform cull strip: 16 wide, 4 tall
  const float wxmin = (float)(blockIdx.x*16);
  const float wxmax = wxmin + 15.0f;
  const float wymin = (float)(blockIdx.y*8 + (ty & 4));
  const float wymax = wymin + 3.0f;

  float4 a0={0,0,0,0}, a1={0,0,0,0}, a2={0,0,0,0}, a3={0,0,0,0}, a4={0,0,0,0},
         a5={0,0,0,0}, a6={0,0,0,0}, a7={0,0,0,0}, a8={0,0,0,0}, a9={0,0,0,0},
         a10={0,0,0,0}, a11={0,0,0,0}, a12={0,0,0,0}, a13={0,0,0,0}, a14={0,0,0,0};
  float T = 1.0f;        // transmittance = 1 - A
  float dacc = 0.0f;
  const int cbase = h*60;
  const float* rowbase = spec + cbase;

  for (int g = 0; g < N_G; ++g) {
    float4 b = bb[g];   // uniform index -> s_load_dwordx4, scalar-cache hot
    if (b.x > wxmax || b.y < wxmin || b.z > wymax || b.w < wymin) continue;
    float4 p = pc[g];
    float4 o = od[g];
    float dx = px - p.x, dy = py - p.y;
    float m = p.z*dx*dx + p.w*dy*dy;
    float alpha = o.x * __expf(-0.5f*m) * T;
    T -= alpha;
    dacc = fmaf(o.y, alpha, dacc);
    const float* row = rowbase + __float_as_int(o.z)*N_C;
    ACC4(0)  ACC4(1)  ACC4(2)  ACC4(3)  ACC4(4)
    ACC4(5)  ACC4(6)  ACC4(7)  ACC4(8)  ACC4(9)
    ACC4(10) ACC4(11) ACC4(12) ACC4(13) ACC4(14)
  }

  if (inb) {
    const int pixi = y*IMG_W + x;
    const float bgT = T;             // BG * (1 - A_final), BG = 1.0
    const float* tmh = tm + cbase;
    ST4(0)  ST4(1)  ST4(2)  ST4(3)  ST4(4)
    ST4(5)  ST4(6)  ST4(7)  ST4(8)  ST4(9)
    ST4(10) ST4(11) ST4(12) ST4(13) ST4(14)
    if (h == 0) out[N_C*HW + pixi] = dacc;            // depth image
    else        out[N_C*HW + HW + pixi] = 1.0f - T;   // A_final
  }
}

extern "C" void kernel_launch(void* const* d_in, const int* in_sizes, int n_in,
                              void* d_out, int out_size, void* d_ws, size_t ws_size,
                              hipStream_t stream) {
  const float* pos    = (const float*)d_in[0];
  // d_in[1] rotations: unused by the reference
  const float* scales = (const float*)d_in[2];
  const float* opac   = (const float*)d_in[3];
  const float* spec   = (const float*)d_in[4];
  const float* tm     = (const float*)d_in[5];
  const float* K      = (const float*)d_in[6];
  const float* E      = (const float*)d_in[7];
  float* out = (float*)d_out;

  float4* bb = (float4*)d_ws;
  float4* pc = bb + N_G;
  float4* od = pc + N_G;

  k_prep<<<1, 512, 0, stream>>>(pos, scales, opac, K, E, bb, pc, od);
  dim3 grid((IMG_W + 15)/16, (IMG_H + 7)/8);
  k_render<<<grid, 256, 0, stream>>>(bb, pc, od, spec, tm, out);
}

// Round 3
// 216.300 us; speedup vs baseline: 2.2831x; 1.2089x over previous
//
#include <hip/hip_runtime.h>
#include <math.h>

#define N_G 512
#define IMG_H 324
#define IMG_W 332
#define N_C 120
#define HW (IMG_H*IMG_W)

// ws layout (all depth-sorted by k_prep):
//   bb : [512] float4 {xmin, xmax, ymin, ymax}   cull bbox (6-sigma; empty if skip)
//   pc : [512] float4 {sx, sy, c00, c11}
//   od : [512] float4 {op, depth, src_idx_bits, 0}

// Rank sort: O(N^2) compares but ONE barrier (vs bitonic's 45 on a single CU).
__global__ __launch_bounds__(512) void k_prep(
    const float* __restrict__ pos, const float* __restrict__ scales,
    const float* __restrict__ opac, const float* __restrict__ K,
    const float* __restrict__ E,
    float4* __restrict__ bb, float4* __restrict__ pc, float4* __restrict__ od)
{
  __shared__ float key[N_G];
  const int i = threadIdx.x;

  float p0 = pos[i*3+0], p1 = pos[i*3+1], p2 = pos[i*3+2];
  float cam0 = E[0]*p0 + E[1]*p1 + E[2]*p2  + E[3];
  float cam1 = E[4]*p0 + E[5]*p1 + E[6]*p2  + E[7];
  float cam2 = E[8]*p0 + E[9]*p1 + E[10]*p2 + E[11];
  float pr0 = K[0]*cam0 + K[1]*cam1 + K[2]*cam2;
  float pr1 = K[3]*cam0 + K[4]*cam1 + K[5]*cam2;
  float pr2 = K[6]*cam0 + K[7]*cam1 + K[8]*cam2;
  float inv = 1.0f/(pr2 + 1e-6f);
  float sx = pr0*inv, sy = pr1*inv;
  float depth = cam2;

  bool valid = (depth > 0.01f) && (depth < 100.0f)
            && (sx > -100.0f) && (sx < (float)IMG_W + 100.0f)
            && (sy > -100.0f) && (sy < (float)IMG_H + 100.0f);
  bool off = (sx < -(float)IMG_W) || (sx > 2.0f*(float)IMG_W)
          || (sy < -(float)IMG_H) || (sy > 2.0f*(float)IMG_H);
  bool skip = off || (!valid);

  float s0 = scales[i*3+0], s1 = scales[i*3+1];
  float v0 = s0*s0 + 1e-4f, v1 = s1*s1 + 1e-4f;
  float c00 = 1.0f/v0, c11 = 1.0f/v1;
  float op = skip ? 0.0f : opac[i];
  float rx = 6.0f*sqrtf(v0);   // mahal cutoff 36 -> alpha_raw < 1.6e-8
  float ry = 6.0f*sqrtf(v1);
  float xmin = skip ?  1e9f : sx - rx;
  float xmax = skip ? -1e9f : sx + rx;
  float ymin = skip ?  1e9f : sy - ry;
  float ymax = skip ? -1e9f : sy + ry;

  key[i] = depth;
  __syncthreads();

  int rank = 0;
  #pragma unroll 8
  for (int j = 0; j < N_G; ++j) {
    float dj = key[j];                       // broadcast LDS read
    rank += (dj < depth || (dj == depth && j < i)) ? 1 : 0;
  }

  bb[rank] = make_float4(xmin, xmax, ymin, ymax);
  pc[rank] = make_float4(sx, sy, c00, c11);
  od[rank] = make_float4(op, depth, __int_as_float(i), 0.0f);
}

// block = 16x4 pixel strip, 256 threads = 64 px * {seg:2} * {half:2}.
// Alpha compositing is associative: (T,acc)@(T',acc') = (T*T', acc + T*acc').
// seg0 does gaussians [0,256), seg1 [256,512); combine seg1 into seg0 via LDS.
#define ACC4(i) \
  { float4 s4 = *(const float4*)(row + 4*(i)); \
    a##i.x = fmaf(alpha, s4.x, a##i.x); \
    a##i.y = fmaf(alpha, s4.y, a##i.y); \
    a##i.z = fmaf(alpha, s4.z, a##i.z); \
    a##i.w = fmaf(alpha, s4.w, a##i.w); }

#define WR4(i) \
  { slot[4*(i)+0]=a##i.x; slot[4*(i)+1]=a##i.y; \
    slot[4*(i)+2]=a##i.z; slot[4*(i)+3]=a##i.w; }

#define CMB4(i) \
  { float4 t4 = *(const float4*)(tmh + 4*(i)); \
    out[(cbase + 4*(i) + 0)*HW + pixi] = (fmaf(T, slot[4*(i)+0], a##i.x) + bgT)*t4.x; \
    out[(cbase + 4*(i) + 1)*HW + pixi] = (fmaf(T, slot[4*(i)+1], a##i.y) + bgT)*t4.y; \
    out[(cbase + 4*(i) + 2)*HW + pixi] = (fmaf(T, slot[4*(i)+2], a##i.z) + bgT)*t4.z; \
    out[(cbase + 4*(i) + 3)*HW + pixi] = (fmaf(T, slot[4*(i)+3], a##i.w) + bgT)*t4.w; }

#define LSTRIDE 63   // 63 floats/slot: gcd(63,32)=1 -> conflict-free lane access

__global__ __launch_bounds__(256, 2) void k_render(
    const float4* __restrict__ bb, const float4* __restrict__ pc,
    const float4* __restrict__ od, const float* __restrict__ spec,
    const float* __restrict__ tm, float* __restrict__ out)
{
  __shared__ float lds[2*64*LSTRIDE];   // [half][pixel][60 acc + T + dacc]

  const int tid  = threadIdx.x;
  const int seg  = tid >> 7;          // depth segment
  const int h    = (tid >> 6) & 1;    // channel half: 0 -> 0..59, 1 -> 60..119
  const int lane = tid & 63;
  const int tx = lane & 15;
  const int ty = lane >> 4;
  const int x = blockIdx.x*16 + tx;
  const int y = blockIdx.y*4 + ty;
  const bool inb = (x < IMG_W) && (y < IMG_H);
  const float px = (float)min(x, IMG_W-1);
  const float py = (float)min(y, IMG_H-1);

  // strip bbox is block-uniform -> scalar compare + s_cbranch per gaussian
  const float wxmin = (float)(blockIdx.x*16), wxmax = wxmin + 15.0f;
  const float wymin = (float)(blockIdx.y*4),  wymax = wymin + 3.0f;

  float4 a0={0,0,0,0}, a1={0,0,0,0}, a2={0,0,0,0}, a3={0,0,0,0}, a4={0,0,0,0},
         a5={0,0,0,0}, a6={0,0,0,0}, a7={0,0,0,0}, a8={0,0,0,0}, a9={0,0,0,0},
         a10={0,0,0,0}, a11={0,0,0,0}, a12={0,0,0,0}, a13={0,0,0,0}, a14={0,0,0,0};
  float T = 1.0f;
  float dacc = 0.0f;
  const int cbase = h*60;
  const float* rowbase = spec + cbase;

  const int g0 = seg*(N_G/2), g1 = g0 + N_G/2;
  for (int g = g0; g < g1; ++g) {
    float4 b = bb[g];   // uniform index -> s_load_dwordx4
    if (b.x > wxmax || b.y < wxmin || b.z > wymax || b.w < wymin) continue;
    float4 p = pc[g];
    float4 o = od[g];
    float dx = px - p.x, dy = py - p.y;
    float m = p.z*dx*dx + p.w*dy*dy;
    float alpha = o.x * __expf(-0.5f*m) * T;
    T -= alpha;
    dacc = fmaf(o.y, alpha, dacc);
    const float* row = rowbase + __float_as_int(o.z)*N_C;
    ACC4(0)  ACC4(1)  ACC4(2)  ACC4(3)  ACC4(4)
    ACC4(5)  ACC4(6)  ACC4(7)  ACC4(8)  ACC4(9)
    ACC4(10) ACC4(11) ACC4(12) ACC4(13) ACC4(14)
  }

  float* slot = &lds[(h*64 + lane)*LSTRIDE];
  if (seg == 1) {
    WR4(0)  WR4(1)  WR4(2)  WR4(3)  WR4(4)
    WR4(5)  WR4(6)  WR4(7)  WR4(8)  WR4(9)
    WR4(10) WR4(11) WR4(12) WR4(13) WR4(14)
    slot[60] = T; slot[61] = dacc;
  }
  __syncthreads();

  if (seg == 0 && inb) {
    const int pixi = y*IMG_W + x;
    const float Tb = slot[60], db = slot[61];
    const float Tf = T * Tb;        // final transmittance
    const float bgT = Tf;           // BG * (1 - A_final) with BG = 1.0
    const float* tmh = tm + cbase;
    CMB4(0)  CMB4(1)  CMB4(2)  CMB4(3)  CMB4(4)
    CMB4(5)  CMB4(6)  CMB4(7)  CMB4(8)  CMB4(9)
    CMB4(10) CMB4(11) CMB4(12) CMB4(13) CMB4(14)
    if (h == 0) out[N_C*HW + pixi] = fmaf(T, db, dacc);   // depth image
    else        out[N_C*HW + HW + pixi] = 1.0f - Tf;      // A_final
  }
}

extern "C" void kernel_launch(void* const* d_in, const int* in_sizes, int n_in,
                              void* d_out, int out_size, void* d_ws, size_t ws_size,
                              hipStream_t stream) {
  const float* pos    = (const float*)d_in[0];
  // d_in[1] rotations: unused by the reference
  const float* scales = (const float*)d_in[2];
  const float* opac   = (const float*)d_in[3];
  const float* spec   = (const float*)d_in[4];
  const float* tm     = (const float*)d_in[5];
  const float* K      = (const float*)d_in[6];
  const float* E      = (const float*)d_in[7];
  float* out = (float*)d_out;

  float4* bb = (float4*)d_ws;
  float4* pc = bb + N_G;
  float4* od = pc + N_G;

  k_prep<<<1, 512, 0, stream>>>(pos, scales, opac, K, E, bb, pc, od);
  dim3 grid((IMG_W + 15)/16, (IMG_H + 3)/4);
  k_render<<<grid, 256, 0, stream>>>(bb, pc, od, spec, tm, out);
}

// Round 4
// 157.649 us; speedup vs baseline: 3.1326x; 1.3720x over previous
//
#include <hip/hip_runtime.h>
#include <math.h>

#define N_G 512
#define IMG_H 324
#define IMG_W 332
#define N_C 120
#define HW (IMG_H*IMG_W)

// ws layout (all depth-sorted by k_prep):
//   bb : [512] float4 {xmin, xmax, ymin, ymax}   cull bbox (6-sigma; empty if skip)
//   pc : [512] float4 {sx, sy, c00, c11}
//   od : [512] float4 {op, depth, (src*120)_bits, 0}

// Rank sort: O(N^2) compares but ONE barrier.
__global__ __launch_bounds__(512) void k_prep(
    const float* __restrict__ pos, const float* __restrict__ scales,
    const float* __restrict__ opac, const float* __restrict__ K,
    const float* __restrict__ E,
    float4* __restrict__ bb, float4* __restrict__ pc, float4* __restrict__ od)
{
  __shared__ float key[N_G];
  const int i = threadIdx.x;

  float p0 = pos[i*3+0], p1 = pos[i*3+1], p2 = pos[i*3+2];
  float cam0 = E[0]*p0 + E[1]*p1 + E[2]*p2  + E[3];
  float cam1 = E[4]*p0 + E[5]*p1 + E[6]*p2  + E[7];
  float cam2 = E[8]*p0 + E[9]*p1 + E[10]*p2 + E[11];
  float pr0 = K[0]*cam0 + K[1]*cam1 + K[2]*cam2;
  float pr1 = K[3]*cam0 + K[4]*cam1 + K[5]*cam2;
  float pr2 = K[6]*cam0 + K[7]*cam1 + K[8]*cam2;
  float inv = 1.0f/(pr2 + 1e-6f);
  float sx = pr0*inv, sy = pr1*inv;
  float depth = cam2;

  bool valid = (depth > 0.01f) && (depth < 100.0f)
            && (sx > -100.0f) && (sx < (float)IMG_W + 100.0f)
            && (sy > -100.0f) && (sy < (float)IMG_H + 100.0f);
  bool off = (sx < -(float)IMG_W) || (sx > 2.0f*(float)IMG_W)
          || (sy < -(float)IMG_H) || (sy > 2.0f*(float)IMG_H);
  bool skip = off || (!valid);

  float s0 = scales[i*3+0], s1 = scales[i*3+1];
  float v0 = s0*s0 + 1e-4f, v1 = s1*s1 + 1e-4f;
  float c00 = 1.0f/v0, c11 = 1.0f/v1;
  float op = skip ? 0.0f : opac[i];
  float rx = 6.0f*sqrtf(v0);   // mahal cutoff 36 -> alpha_raw < 1.6e-8
  float ry = 6.0f*sqrtf(v1);
  float xmin = skip ?  1e9f : sx - rx;
  float xmax = skip ? -1e9f : sx + rx;
  float ymin = skip ?  1e9f : sy - ry;
  float ymax = skip ? -1e9f : sy + ry;

  key[i] = depth;
  __syncthreads();

  int rank = 0;
  #pragma unroll 8
  for (int j = 0; j < N_G; ++j) {
    float dj = key[j];
    rank += (dj < depth || (dj == depth && j < i)) ? 1 : 0;
  }

  bb[rank] = make_float4(xmin, xmax, ymin, ymax);
  pc[rank] = make_float4(sx, sy, c00, c11);
  od[rank] = make_float4(op, depth, __int_as_float(i*N_C), 0.0f);
}

// block = 16x4 pixel strip, 256 threads = 64 px * {seg:2} * {half:2}.
// Alpha compositing is associative: (T,acc)@(T',acc') = (T*T', acc + T*acc').
#define ACC4(i) \
  { float4 s4 = *(const float4*)(row + 4*(i)); \
    a##i.x = fmaf(alpha, s4.x, a##i.x); \
    a##i.y = fmaf(alpha, s4.y, a##i.y); \
    a##i.z = fmaf(alpha, s4.z, a##i.z); \
    a##i.w = fmaf(alpha, s4.w, a##i.w); }

#define WR4(i) \
  { slot[4*(i)+0]=a##i.x; slot[4*(i)+1]=a##i.y; \
    slot[4*(i)+2]=a##i.z; slot[4*(i)+3]=a##i.w; }

#define CMB4(i) \
  { float4 t4 = *(const float4*)(tmh + 4*(i)); \
    out[(cbase + 4*(i) + 0)*HW + pixi] = (fmaf(T, slot[4*(i)+0], a##i.x) + bgT)*t4.x; \
    out[(cbase + 4*(i) + 1)*HW + pixi] = (fmaf(T, slot[4*(i)+1], a##i.y) + bgT)*t4.y; \
    out[(cbase + 4*(i) + 2)*HW + pixi] = (fmaf(T, slot[4*(i)+2], a##i.z) + bgT)*t4.z; \
    out[(cbase + 4*(i) + 3)*HW + pixi] = (fmaf(T, slot[4*(i)+3], a##i.w) + bgT)*t4.w; }

#define LSTRIDE 63   // 63 floats/slot: conflict-free lane access

__global__ __launch_bounds__(256, 2) void k_render(
    const float4* __restrict__ bb, const float4* __restrict__ pc,
    const float4* __restrict__ od, const float* __restrict__ spec,
    const float* __restrict__ tm, float* __restrict__ out)
{
  __shared__ float lds[2*64*LSTRIDE];   // [half][pixel][60 acc + T + dacc]
  __shared__ unsigned short hlist[2][256];
  __shared__ int hcnt[2];

  const int tid  = threadIdx.x;
  const int seg  = tid >> 7;          // depth segment: [0,256) or [256,512)
  const int h    = (tid >> 6) & 1;    // channel half
  const int lane = tid & 63;
  const int tx = lane & 15;
  const int ty = lane >> 4;
  const int x = blockIdx.x*16 + tx;
  const int y = blockIdx.y*4 + ty;
  const bool inb = (x < IMG_W) && (y < IMG_H);
  const float px = (float)min(x, IMG_W-1);
  const float py = (float)min(y, IMG_H-1);

  const float wxmin = (float)(blockIdx.x*16), wxmax = wxmin + 15.0f;
  const float wymin = (float)(blockIdx.y*4),  wymax = wymin + 3.0f;

  // ---- build compacted hit list (order-preserving), one wave per segment ----
  if (h == 0) {
    int base = 0;
    #pragma unroll
    for (int r = 0; r < 4; ++r) {
      int g = seg*256 + r*64 + lane;
      float4 b = bb[g];                         // coalesced dwordx4
      bool hit = !(b.x > wxmax || b.y < wxmin || b.z > wymax || b.w < wymin);
      unsigned long long bm = __ballot(hit);
      int pos = base + __popcll(bm & ((1ull << lane) - 1ull));
      if (hit) hlist[seg][pos] = (unsigned short)g;
      base += __popcll(bm);
    }
    if (lane == 0) hcnt[seg] = base;
  }
  __syncthreads();
  const int nh = hcnt[seg];

  float4 a0={0,0,0,0}, a1={0,0,0,0}, a2={0,0,0,0}, a3={0,0,0,0}, a4={0,0,0,0},
         a5={0,0,0,0}, a6={0,0,0,0}, a7={0,0,0,0}, a8={0,0,0,0}, a9={0,0,0,0},
         a10={0,0,0,0}, a11={0,0,0,0}, a12={0,0,0,0}, a13={0,0,0,0}, a14={0,0,0,0};
  float T = 1.0f;
  float dacc = 0.0f;
  const int cbase = h*60;
  const float* rowbase = spec + cbase;

  // ---- dense, branch-free composite over the hit list ----
  for (int i = 0; i < nh; ++i) {
    int g = __builtin_amdgcn_readfirstlane((int)hlist[seg][i]);
    float4 p = pc[g];                 // uniform -> s_load_dwordx4
    float4 o = od[g];
    float dx = px - p.x, dy = py - p.y;
    float m = p.z*dx*dx + p.w*dy*dy;
    float alpha = o.x * __expf(-0.5f*m) * T;
    T -= alpha;
    dacc = fmaf(o.y, alpha, dacc);
    const float* row = rowbase + __float_as_int(o.z);   // o.z = src*120
    ACC4(0)  ACC4(1)  ACC4(2)  ACC4(3)  ACC4(4)
    ACC4(5)  ACC4(6)  ACC4(7)  ACC4(8)  ACC4(9)
    ACC4(10) ACC4(11) ACC4(12) ACC4(13) ACC4(14)
  }

  float* slot = &lds[(h*64 + lane)*LSTRIDE];
  if (seg == 1) {
    WR4(0)  WR4(1)  WR4(2)  WR4(3)  WR4(4)
    WR4(5)  WR4(6)  WR4(7)  WR4(8)  WR4(9)
    WR4(10) WR4(11) WR4(12) WR4(13) WR4(14)
    slot[60] = T; slot[61] = dacc;
  }
  __syncthreads();

  if (seg == 0 && inb) {
    const int pixi = y*IMG_W + x;
    const float Tb = slot[60], db = slot[61];
    const float Tf = T * Tb;        // final transmittance
    const float bgT = Tf;           // BG * (1 - A_final), BG = 1.0
    const float* tmh = tm + cbase;
    CMB4(0)  CMB4(1)  CMB4(2)  CMB4(3)  CMB4(4)
    CMB4(5)  CMB4(6)  CMB4(7)  CMB4(8)  CMB4(9)
    CMB4(10) CMB4(11) CMB4(12) CMB4(13) CMB4(14)
    if (h == 0) out[N_C*HW + pixi] = fmaf(T, db, dacc);   // depth image
    else        out[N_C*HW + HW + pixi] = 1.0f - Tf;      // A_final
  }
}

extern "C" void kernel_launch(void* const* d_in, const int* in_sizes, int n_in,
                              void* d_out, int out_size, void* d_ws, size_t ws_size,
                              hipStream_t stream) {
  const float* pos    = (const float*)d_in[0];
  // d_in[1] rotations: unused by the reference
  const float* scales = (const float*)d_in[2];
  const float* opac   = (const float*)d_in[3];
  const float* spec   = (const float*)d_in[4];
  const float* tm     = (const float*)d_in[5];
  const float* K      = (const float*)d_in[6];
  const float* E      = (const float*)d_in[7];
  float* out = (float*)d_out;

  float4* bb = (float4*)d_ws;
  float4* pc = bb + N_G;
  float4* od = pc + N_G;

  k_prep<<<1, 512, 0, stream>>>(pos, scales, opac, K, E, bb, pc, od);
  dim3 grid((IMG_W + 15)/16, (IMG_H + 3)/4);
  k_render<<<grid, 256, 0, stream>>>(bb, pc, od, spec, tm, out);
}

// Round 5
// 143.113 us; speedup vs baseline: 3.4507x; 1.1016x over previous
//
#include <hip/hip_runtime.h>
#include <math.h>

#define N_G 512
#define IMG_H 324
#define IMG_W 332
#define N_C 120
#define HW (IMG_H*IMG_W)
#define CHUNK 128

// ws layout (all depth-sorted by k_prep):
//   bb : [512] float4 {xmin, xmax, ymin, ymax}   cull bbox (6-sigma; empty if skip)
//   pc : [512] float4 {sx, sy, c00, c11}
//   od : [512] float4 {op, depth, (src*120)_bits, 0}

// Rank sort: O(N^2) compares but ONE barrier.
__global__ __launch_bounds__(512) void k_prep(
    const float* __restrict__ pos, const float* __restrict__ scales,
    const float* __restrict__ opac, const float* __restrict__ K,
    const float* __restrict__ E,
    float4* __restrict__ bb, float4* __restrict__ pc, float4* __restrict__ od)
{
  __shared__ float key[N_G];
  const int i = threadIdx.x;

  float p0 = pos[i*3+0], p1 = pos[i*3+1], p2 = pos[i*3+2];
  float cam0 = E[0]*p0 + E[1]*p1 + E[2]*p2  + E[3];
  float cam1 = E[4]*p0 + E[5]*p1 + E[6]*p2  + E[7];
  float cam2 = E[8]*p0 + E[9]*p1 + E[10]*p2 + E[11];
  float pr0 = K[0]*cam0 + K[1]*cam1 + K[2]*cam2;
  float pr1 = K[3]*cam0 + K[4]*cam1 + K[5]*cam2;
  float pr2 = K[6]*cam0 + K[7]*cam1 + K[8]*cam2;
  float inv = 1.0f/(pr2 + 1e-6f);
  float sx = pr0*inv, sy = pr1*inv;
  float depth = cam2;

  bool valid = (depth > 0.01f) && (depth < 100.0f)
            && (sx > -100.0f) && (sx < (float)IMG_W + 100.0f)
            && (sy > -100.0f) && (sy < (float)IMG_H + 100.0f);
  bool off = (sx < -(float)IMG_W) || (sx > 2.0f*(float)IMG_W)
          || (sy < -(float)IMG_H) || (sy > 2.0f*(float)IMG_H);
  bool skip = off || (!valid);

  float s0 = scales[i*3+0], s1 = scales[i*3+1];
  float v0 = s0*s0 + 1e-4f, v1 = s1*s1 + 1e-4f;
  float c00 = 1.0f/v0, c11 = 1.0f/v1;
  float op = skip ? 0.0f : opac[i];
  float rx = 6.0f*sqrtf(v0);   // mahal cutoff 36 -> alpha_raw < 1.6e-8
  float ry = 6.0f*sqrtf(v1);
  float xmin = skip ?  1e9f : sx - rx;
  float xmax = skip ? -1e9f : sx + rx;
  float ymin = skip ?  1e9f : sy - ry;
  float ymax = skip ? -1e9f : sy + ry;

  key[i] = depth;
  __syncthreads();

  int rank = 0;
  #pragma unroll 8
  for (int j = 0; j < N_G; ++j) {
    float dj = key[j];
    rank += (dj < depth || (dj == depth && j < i)) ? 1 : 0;
  }

  bb[rank] = make_float4(xmin, xmax, ymin, ymax);
  pc[rank] = make_float4(sx, sy, c00, c11);
  od[rank] = make_float4(op, depth, __int_as_float(i*N_C), 0.0f);
}

// block = 16x4 px strip, 256 threads = 4 waves; lane = pixel.
// wave w: h = w&1 (channel half), s = w>>1 (hit parity for phase 2).
// Phase 1a: araw[j][p] in parallel (no serial dep).
// Phase 1b: wave 0 per-pixel cumprod, araw -> w in place; dacc, T.
// Phase 2:  acc_c += w_j * spec[j][c] -- pure FMA streaming, partials add.
#define ACC4(i) \
  { float4 s4 = *(const float4*)(row + 4*(i)); \
    a##i.x = fmaf(wv, s4.x, a##i.x); \
    a##i.y = fmaf(wv, s4.y, a##i.y); \
    a##i.z = fmaf(wv, s4.z, a##i.z); \
    a##i.w = fmaf(wv, s4.w, a##i.w); }

#define WR4(i) \
  { slot[4*(i)+0]=a##i.x; slot[4*(i)+1]=a##i.y; \
    slot[4*(i)+2]=a##i.z; slot[4*(i)+3]=a##i.w; }

#define CMB4(i) \
  { float4 t4 = *(const float4*)(tmh + 4*(i)); \
    out[(cbase + 4*(i) + 0)*HW + pixi] = (a##i.x + slot[4*(i)+0] + bgT)*t4.x; \
    out[(cbase + 4*(i) + 1)*HW + pixi] = (a##i.y + slot[4*(i)+1] + bgT)*t4.y; \
    out[(cbase + 4*(i) + 2)*HW + pixi] = (a##i.z + slot[4*(i)+2] + bgT)*t4.z; \
    out[(cbase + 4*(i) + 3)*HW + pixi] = (a##i.w + slot[4*(i)+3] + bgT)*t4.w; }

__global__ __launch_bounds__(256, 2) void k_render(
    const float4* __restrict__ bb, const float4* __restrict__ pc,
    const float4* __restrict__ od, const float* __restrict__ spec,
    const float* __restrict__ tm, float* __restrict__ out)
{
  __shared__ float buf[CHUNK*64];        // araw -> w in place; reused for partials
  __shared__ float dep[CHUNK];
  __shared__ int   srow[CHUNK];
  __shared__ unsigned short hlist[N_G];
  __shared__ int hcnt;
  __shared__ float Tcar[64], Dcar[64];

  const int tid  = threadIdx.x;
  const int w    = tid >> 6;
  const int lane = tid & 63;
  const int h    = w & 1;
  const int s    = w >> 1;
  const int tx = lane & 15, ty = lane >> 4;
  const int x = blockIdx.x*16 + tx;
  const int y = blockIdx.y*4 + ty;
  const bool inb = (x < IMG_W) && (y < IMG_H);
  const float px = (float)min(x, IMG_W-1);
  const float py = (float)min(y, IMG_H-1);

  const float wxmin = (float)(blockIdx.x*16), wxmax = wxmin + 15.0f;
  const float wymin = (float)(blockIdx.y*4),  wymax = wymin + 3.0f;

  // ---- hit list (order-preserving ballot compaction), wave 0 ----
  if (w == 0) {
    int base = 0;
    #pragma unroll
    for (int r = 0; r < 8; ++r) {
      int g = r*64 + lane;
      float4 b = bb[g];                          // coalesced dwordx4
      bool hit = !(b.x > wxmax || b.y < wxmin || b.z > wymax || b.w < wymin);
      unsigned long long bm = __ballot(hit);
      int pos = base + __popcll(bm & ((1ull << lane) - 1ull));
      if (hit) hlist[pos] = (unsigned short)g;
      base += __popcll(bm);
    }
    if (lane == 0) hcnt = base;
  }
  __syncthreads();
  const int nh = hcnt;

  float T = 1.0f, dacc = 0.0f;   // meaningful in wave 0 only (lane = pixel)

  float4 a0={0,0,0,0}, a1={0,0,0,0}, a2={0,0,0,0}, a3={0,0,0,0}, a4={0,0,0,0},
         a5={0,0,0,0}, a6={0,0,0,0}, a7={0,0,0,0}, a8={0,0,0,0}, a9={0,0,0,0},
         a10={0,0,0,0}, a11={0,0,0,0}, a12={0,0,0,0}, a13={0,0,0,0}, a14={0,0,0,0};
  const int cbase = h*60;
  const float* rowbase = spec + cbase;

  for (int cb = 0; cb < nh; cb += CHUNK) {
    const int nc = min(CHUNK, nh - cb);

    // ---- phase 1a: araw for this chunk, 4 waves interleaved ----
    for (int j = w; j < nc; j += 4) {
      int g = __builtin_amdgcn_readfirstlane((int)hlist[cb + j]);
      float4 p = pc[g];            // uniform -> s_load_dwordx4
      float4 o = od[g];
      float dx = px - p.x, dy = py - p.y;
      float m = p.z*dx*dx + p.w*dy*dy;
      float ar = o.x * __expf(-0.5f*m);
      buf[j*64 + lane] = ar;       // stride-1 lanes: conflict-free
      if (lane == 0) { dep[j] = o.y; srow[j] = __float_as_int(o.z); }
    }
    __syncthreads();

    // ---- phase 1b: per-pixel cumprod (wave 0): araw -> w in place ----
    if (w == 0) {
      for (int j = 0; j < nc; ++j) {
        float a = buf[j*64 + lane];
        float wv = a * T;
        buf[j*64 + lane] = wv;
        T -= wv;                    // T *= (1 - a)
        dacc = fmaf(dep[j], wv, dacc);
      }
    }
    __syncthreads();

    // ---- phase 2: dense weighted accumulation, no serial deps ----
    for (int j = s; j < nc; j += 2) {
      int gs = __builtin_amdgcn_readfirstlane(srow[j]);   // src*120
      float wv = buf[j*64 + lane];
      const float* row = rowbase + gs;
      ACC4(0)  ACC4(1)  ACC4(2)  ACC4(3)  ACC4(4)
      ACC4(5)  ACC4(6)  ACC4(7)  ACC4(8)  ACC4(9)
      ACC4(10) ACC4(11) ACC4(12) ACC4(13) ACC4(14)
    }
    __syncthreads();
  }

  // ---- epilogue: combine hit-parity partials (pure add), store ----
  if (w == 0) { Tcar[lane] = T; Dcar[lane] = dacc; }
  if (s == 1) {
    float* slot = &buf[(h*64 + lane)*61];   // stride 61: conflict-free
    WR4(0)  WR4(1)  WR4(2)  WR4(3)  WR4(4)
    WR4(5)  WR4(6)  WR4(7)  WR4(8)  WR4(9)
    WR4(10) WR4(11) WR4(12) WR4(13) WR4(14)
  }
  __syncthreads();

  if (s == 0 && inb) {
    const int pixi = y*IMG_W + x;
    const float Tf = Tcar[lane];
    const float bgT = Tf;                   // BG * (1 - A_final), BG = 1.0
    const float* tmh = tm + cbase;
    const float* slot = &buf[(h*64 + lane)*61];
    CMB4(0)  CMB4(1)  CMB4(2)  CMB4(3)  CMB4(4)
    CMB4(5)  CMB4(6)  CMB4(7)  CMB4(8)  CMB4(9)
    CMB4(10) CMB4(11) CMB4(12) CMB4(13) CMB4(14)
    if (h == 0) out[N_C*HW + pixi] = Dcar[lane];      // depth image
    else        out[N_C*HW + HW + pixi] = 1.0f - Tf;  // A_final
  }
}

extern "C" void kernel_launch(void* const* d_in, const int* in_sizes, int n_in,
                              void* d_out, int out_size, void* d_ws, size_t ws_size,
                              hipStream_t stream) {
  const float* pos    = (const float*)d_in[0];
  // d_in[1] rotations: unused by the reference
  const float* scales = (const float*)d_in[2];
  const float* opac   = (const float*)d_in[3];
  const float* spec   = (const float*)d_in[4];
  const float* tm     = (const float*)d_in[5];
  const float* K      = (const float*)d_in[6];
  const float* E      = (const float*)d_in[7];
  float* out = (float*)d_out;

  float4* bb = (float4*)d_ws;
  float4* pc = bb + N_G;
  float4* od = pc + N_G;

  k_prep<<<1, 512, 0, stream>>>(pos, scales, opac, K, E, bb, pc, od);
  dim3 grid((IMG_W + 15)/16, (IMG_H + 3)/4);
  k_render<<<grid, 256, 0, stream>>>(bb, pc, od, spec, tm, out);
}